// Round 2
// baseline (10648.505 us; speedup 1.0000x reference)
//
#include <hip/hip_runtime.h>
#include <math.h>

#define EMB 32
#define HID 16
#define BY 4
#define NSYMP 15
#define NOPT 3
#define XCOLS (BY + 1 + NSYMP)   // 20

// ---------------- degree count (uint atomics over tgt) ----------------
__global__ __launch_bounds__(256) void k_deg(const int* __restrict__ tgt,
                                             unsigned int* __restrict__ deg, int nE) {
    int e = blockIdx.x * blockDim.x + threadIdx.x;
    if (e < nE) atomicAdd(&deg[tgt[e]], 1u);
}

// ---------------- dinv = rsqrt(deg + 1 self-loop), Newton-refined ----------------
__global__ __launch_bounds__(256) void k_dinv(unsigned int* __restrict__ deg_io,
                                              float* __restrict__ dinv, int n) {
    int i = blockIdx.x * blockDim.x + threadIdx.x;
    if (i < n) {
        float d = (float)(deg_io[i] + 1u);
        float r = rsqrtf(d);
        r = r * (1.5f - 0.5f * d * r * r);   // one Newton step -> ~1 ulp
        dinv[i] = r;
    }
}

// ---------------- embeddings + h@W1, pre-scaled by dinv ----------------
__global__ __launch_bounds__(256) void k_embed(const int* __restrict__ x,
                                               const float* __restrict__ birth_t,
                                               const float* __restrict__ gender_t,
                                               const float* __restrict__ symp_t,
                                               const float* __restrict__ W1,
                                               const float* __restrict__ dinv,
                                               float* __restrict__ hs1, int n) {
    __shared__ float sB[BY * EMB];
    __shared__ float sG[2 * EMB];
    __shared__ float sS[NSYMP * NOPT * EMB];
    __shared__ float sW[EMB * HID];
    for (int k = threadIdx.x; k < BY * EMB; k += blockDim.x) sB[k] = birth_t[k];
    for (int k = threadIdx.x; k < 2 * EMB; k += blockDim.x) sG[k] = gender_t[k];
    for (int k = threadIdx.x; k < NSYMP * NOPT * EMB; k += blockDim.x) sS[k] = symp_t[k];
    for (int k = threadIdx.x; k < EMB * HID; k += blockDim.x) sW[k] = W1[k];
    __syncthreads();

    int i = blockIdx.x * blockDim.x + threadIdx.x;
    if (i >= n) return;

    const int* xr = x + (size_t)i * XCOLS;
    int xv[XCOLS];
#pragma unroll
    for (int k = 0; k < XCOLS; ++k) xv[k] = xr[k];

    // argmax over the one-hot birth columns (first max == the single 1)
    int bi = 0;
#pragma unroll
    for (int k = 1; k < BY; ++k) if (xv[k] > xv[bi]) bi = k;
    int gi = xv[BY];

    float ssum[EMB];
#pragma unroll
    for (int k = 0; k < EMB; ++k) ssum[k] = 0.f;
#pragma unroll
    for (int j = 0; j < NSYMP; ++j) {
        const float* row = &sS[(j * NOPT + xv[BY + 1 + j]) * EMB];
#pragma unroll
        for (int k = 0; k < EMB; ++k) ssum[k] += row[k];
    }

    float h[EMB];
#pragma unroll
    for (int k = 0; k < EMB; ++k)
        h[k] = (sB[bi * EMB + k] + sG[gi * EMB + k] + ssum[k] * (1.f / 15.f)) * (1.f / 3.f);

    float hp[HID];
#pragma unroll
    for (int j = 0; j < HID; ++j) hp[j] = 0.f;
#pragma unroll
    for (int k = 0; k < EMB; ++k) {
        float hv = h[k];
#pragma unroll
        for (int j = 0; j < HID; ++j) hp[j] += hv * sW[k * HID + j];
    }

    float dv = dinv[i];
    float4* o = (float4*)(hs1 + (size_t)i * HID);
#pragma unroll
    for (int q = 0; q < 4; ++q) {
        float4 v;
        v.x = dv * hp[q * 4 + 0];
        v.y = dv * hp[q * 4 + 1];
        v.z = dv * hp[q * 4 + 2];
        v.w = dv * hp[q * 4 + 3];
        o[q] = v;
    }
}

// ---------------- edge aggregation: acc[tgt] += hs[src] ----------------
__global__ __launch_bounds__(256) void k_agg(const int* __restrict__ src,
                                             const int* __restrict__ tgt,
                                             const float* __restrict__ hs,
                                             float* __restrict__ acc, int nE) {
    int e = blockIdx.x * blockDim.x + threadIdx.x;
    if (e >= nE) return;
    int s = src[e];
    int t = tgt[e];
    const float4* hr = (const float4*)(hs + (size_t)s * HID);
    float4 a = hr[0], b = hr[1], c = hr[2], d = hr[3];
    float* p = acc + (size_t)t * HID;
    atomicAdd(p + 0, a.x);  atomicAdd(p + 1, a.y);  atomicAdd(p + 2, a.z);  atomicAdd(p + 3, a.w);
    atomicAdd(p + 4, b.x);  atomicAdd(p + 5, b.y);  atomicAdd(p + 6, b.z);  atomicAdd(p + 7, b.w);
    atomicAdd(p + 8, c.x);  atomicAdd(p + 9, c.y);  atomicAdd(p + 10, c.z); atomicAdd(p + 11, c.w);
    atomicAdd(p + 12, d.x); atomicAdd(p + 13, d.y); atomicAdd(p + 14, d.z); atomicAdd(p + 15, d.w);
}

// ---------------- h1 = ELU(dinv*(acc+hs1)+b1); hs2 = dinv*(h1@W2) in-place into A ----------------
__global__ __launch_bounds__(256) void k_mid(const float* __restrict__ accB,
                                             float* __restrict__ A,   // in: hs1, out: hs2
                                             const float* __restrict__ dinv,
                                             const float* __restrict__ W2,
                                             const float* __restrict__ b1, int n) {
    __shared__ float sW[HID * HID];
    __shared__ float sb[HID];
    for (int k = threadIdx.x; k < HID * HID; k += blockDim.x) sW[k] = W2[k];
    if (threadIdx.x < HID) sb[threadIdx.x] = b1[threadIdx.x];
    __syncthreads();

    int i = blockIdx.x * blockDim.x + threadIdx.x;
    if (i >= n) return;

    float dv = dinv[i];
    const float* Ar = A + (size_t)i * HID;
    const float* Br = accB + (size_t)i * HID;
    float h1[HID];
#pragma unroll
    for (int j = 0; j < HID; ++j) {
        float v = dv * (Br[j] + Ar[j]) + sb[j];
        h1[j] = (v > 0.f) ? v : expm1f(v);
    }
    float hp[HID];
#pragma unroll
    for (int j = 0; j < HID; ++j) hp[j] = 0.f;
#pragma unroll
    for (int k = 0; k < HID; ++k) {
        float hv = h1[k];
#pragma unroll
        for (int j = 0; j < HID; ++j) hp[j] += hv * sW[k * HID + j];
    }
    float4* o = (float4*)(A + (size_t)i * HID);
#pragma unroll
    for (int q = 0; q < 4; ++q) {
        float4 v;
        v.x = dv * hp[q * 4 + 0];
        v.y = dv * hp[q * 4 + 1];
        v.z = dv * hp[q * 4 + 2];
        v.w = dv * hp[q * 4 + 3];
        o[q] = v;
    }
}

// ---------------- out = (dinv*(acc+hs2)+b2) @ Wl + bl ----------------
__global__ __launch_bounds__(256) void k_final(const float* __restrict__ accB,
                                               const float* __restrict__ A,
                                               const float* __restrict__ dinv,
                                               const float* __restrict__ b2,
                                               const float* __restrict__ Wl,
                                               const float* __restrict__ bl,
                                               float* __restrict__ out, int n) {
    __shared__ float sW[HID];
    __shared__ float sb[HID];
    __shared__ float sbl;
    if (threadIdx.x < HID) { sW[threadIdx.x] = Wl[threadIdx.x]; sb[threadIdx.x] = b2[threadIdx.x]; }
    if (threadIdx.x == 0) sbl = bl[0];
    __syncthreads();

    int i = blockIdx.x * blockDim.x + threadIdx.x;
    if (i >= n) return;

    float dv = dinv[i];
    const float* Ar = A + (size_t)i * HID;
    const float* Br = accB + (size_t)i * HID;
    float acc = sbl;
#pragma unroll
    for (int j = 0; j < HID; ++j) {
        float v = dv * (Br[j] + Ar[j]) + sb[j];
        acc += v * sW[j];
    }
    out[i] = acc;
}

extern "C" void kernel_launch(void* const* d_in, const int* in_sizes, int n_in,
                              void* d_out, int out_size, void* d_ws, size_t ws_size,
                              hipStream_t stream) {
    const int*   x        = (const int*)d_in[0];
    const int*   ei       = (const int*)d_in[1];   // harness passes integer inputs as int32
    const float* birth_t  = (const float*)d_in[2];
    const float* gender_t = (const float*)d_in[3];
    const float* symp_t   = (const float*)d_in[4];
    const float* W1       = (const float*)d_in[5];
    const float* b1       = (const float*)d_in[6];
    const float* W2       = (const float*)d_in[7];
    const float* b2       = (const float*)d_in[8];
    const float* Wl       = (const float*)d_in[9];
    const float* bl       = (const float*)d_in[10];
    float*       out      = (float*)d_out;

    const int n  = in_sizes[0] / XCOLS;
    const int nE = in_sizes[1] / 2;
    const int* src = ei;
    const int* tgt = ei + nE;

    // workspace layout
    char* ws = (char*)d_ws;
    float* D = (float*)ws;                                        // n floats (aliased uint during deg)
    float* A = (float*)(ws + (((size_t)n * 4 + 255) & ~255ull));  // n*HID floats
    float* B = (float*)((char*)A + (((size_t)n * HID * 4 + 255) & ~255ull)); // n*HID floats

    const int BLK = 256;
    const int gN = (n + BLK - 1) / BLK;
    const int gE = (nE + BLK - 1) / BLK;

    hipMemsetAsync(D, 0, (size_t)n * 4, stream);
    hipMemsetAsync(B, 0, (size_t)n * HID * 4, stream);

    k_deg<<<gE, BLK, 0, stream>>>(tgt, (unsigned int*)D, nE);
    k_dinv<<<gN, BLK, 0, stream>>>((unsigned int*)D, D, n);
    k_embed<<<gN, BLK, 0, stream>>>(x, birth_t, gender_t, symp_t, W1, D, A, n);
    k_agg<<<gE, BLK, 0, stream>>>(src, tgt, A, B, nE);
    k_mid<<<gN, BLK, 0, stream>>>(B, A, D, W2, b1, n);
    hipMemsetAsync(B, 0, (size_t)n * HID * 4, stream);
    k_agg<<<gE, BLK, 0, stream>>>(src, tgt, A, B, nE);
    k_final<<<gN, BLK, 0, stream>>>(B, A, D, b2, Wl, bl, out, n);
}

// Round 3
// 584.033 us; speedup vs baseline: 18.2327x; 18.2327x over previous
//
#include <hip/hip_runtime.h>
#include <math.h>

#define EMB 32
#define HID 16
#define BY 4
#define NSYMP 15
#define NOPT 3
#define XCOLS (BY + 1 + NSYMP)   // 20

#define SCAN_T 256
#define SCAN_E 8
#define SCAN_B (SCAN_T * SCAN_E)  // 2048 elements per block; n <= 128*2048 supported

// ---- pass A: deg[t]++ and remember each edge's slot within its bucket ----
__global__ __launch_bounds__(256) void k_degpos(const int* __restrict__ tgt,
                                                unsigned int* __restrict__ deg,
                                                unsigned int* __restrict__ pos, int nE) {
    int e = blockIdx.x * blockDim.x + threadIdx.x;
    if (e < nE) pos[e] = atomicAdd(&deg[tgt[e]], 1u);
}

// ---- scan step 1: per-block sums of deg ----
__global__ __launch_bounds__(256) void k_bsum(const unsigned int* __restrict__ deg,
                                              unsigned int* __restrict__ bsum, int n) {
    __shared__ unsigned int s[SCAN_T];
    int base = blockIdx.x * SCAN_B + threadIdx.x * SCAN_E;
    unsigned int t = 0;
#pragma unroll
    for (int k = 0; k < SCAN_E; ++k) { int idx = base + k; if (idx < n) t += deg[idx]; }
    s[threadIdx.x] = t; __syncthreads();
    for (int off = SCAN_T / 2; off > 0; off >>= 1) {
        if (threadIdx.x < off) s[threadIdx.x] += s[threadIdx.x + off];
        __syncthreads();
    }
    if (threadIdx.x == 0) bsum[blockIdx.x] = s[0];
}

// ---- scan step 2: exclusive scan of block sums (single block, nb <= 128) ----
__global__ __launch_bounds__(128) void k_bscan(const unsigned int* __restrict__ bsum,
                                               unsigned int* __restrict__ boff, int nb) {
    __shared__ unsigned int s[128];
    unsigned int v = (threadIdx.x < (unsigned)nb) ? bsum[threadIdx.x] : 0u;
    s[threadIdx.x] = v; __syncthreads();
    for (int off = 1; off < 128; off <<= 1) {
        unsigned int t = (threadIdx.x >= (unsigned)off) ? s[threadIdx.x - off] : 0u;
        __syncthreads();
        s[threadIdx.x] += t;
        __syncthreads();
    }
    if (threadIdx.x < (unsigned)nb) boff[threadIdx.x] = s[threadIdx.x] - v;
}

// ---- scan step 3: per-element exclusive prefix -> rowptr ----
__global__ __launch_bounds__(256) void k_scan2(const unsigned int* __restrict__ deg,
                                               const unsigned int* __restrict__ boff,
                                               unsigned int* __restrict__ rowptr, int n, int nE) {
    __shared__ unsigned int s[SCAN_T];
    int tid = threadIdx.x;
    int base = blockIdx.x * SCAN_B + tid * SCAN_E;
    unsigned int loc[SCAN_E];
    unsigned int t = 0;
#pragma unroll
    for (int k = 0; k < SCAN_E; ++k) {
        int idx = base + k;
        unsigned int d = (idx < n) ? deg[idx] : 0u;
        loc[k] = t; t += d;
    }
    s[tid] = t; __syncthreads();
    unsigned int own = t;
    for (int off = 1; off < SCAN_T; off <<= 1) {
        unsigned int u = (tid >= off) ? s[tid - off] : 0u;
        __syncthreads();
        s[tid] += u;
        __syncthreads();
    }
    unsigned int texcl = s[tid] - own;
    unsigned int b = boff[blockIdx.x];
#pragma unroll
    for (int k = 0; k < SCAN_E; ++k) {
        int idx = base + k;
        if (idx < n) rowptr[idx] = b + texcl + loc[k];
    }
    if (blockIdx.x == 0 && tid == 0) rowptr[n] = (unsigned int)nE;
}

// ---- scatter edges into CSR slots (atomic-free) ----
__global__ __launch_bounds__(256) void k_scatter(const int* __restrict__ src,
                                                 const int* __restrict__ tgt,
                                                 const unsigned int* __restrict__ pos,
                                                 const unsigned int* __restrict__ rowptr,
                                                 int* __restrict__ col, int nE) {
    int e = blockIdx.x * blockDim.x + threadIdx.x;
    if (e < nE) col[rowptr[tgt[e]] + pos[e]] = src[e];
}

// ---- dinv = rsqrt(deg + 1 self-loop), Newton-refined ----
__global__ __launch_bounds__(256) void k_dinv(const unsigned int* __restrict__ deg,
                                              float* __restrict__ dinv, int n) {
    int i = blockIdx.x * blockDim.x + threadIdx.x;
    if (i < n) {
        float d = (float)(deg[i] + 1u);
        float r = rsqrtf(d);
        r = r * (1.5f - 0.5f * d * r * r);
        dinv[i] = r;
    }
}

// ---- embeddings + h@W1, pre-scaled by dinv ----
__global__ __launch_bounds__(256) void k_embed(const int* __restrict__ x,
                                               const float* __restrict__ birth_t,
                                               const float* __restrict__ gender_t,
                                               const float* __restrict__ symp_t,
                                               const float* __restrict__ W1,
                                               const float* __restrict__ dinv,
                                               float* __restrict__ hs1, int n) {
    __shared__ float sB[BY * EMB];
    __shared__ float sG[2 * EMB];
    __shared__ float sS[NSYMP * NOPT * EMB];
    __shared__ float sW[EMB * HID];
    for (int k = threadIdx.x; k < BY * EMB; k += blockDim.x) sB[k] = birth_t[k];
    for (int k = threadIdx.x; k < 2 * EMB; k += blockDim.x) sG[k] = gender_t[k];
    for (int k = threadIdx.x; k < NSYMP * NOPT * EMB; k += blockDim.x) sS[k] = symp_t[k];
    for (int k = threadIdx.x; k < EMB * HID; k += blockDim.x) sW[k] = W1[k];
    __syncthreads();

    int i = blockIdx.x * blockDim.x + threadIdx.x;
    if (i >= n) return;

    const int* xr = x + (size_t)i * XCOLS;
    int xv[XCOLS];
#pragma unroll
    for (int k = 0; k < XCOLS; ++k) xv[k] = xr[k];

    int bi = 0;
#pragma unroll
    for (int k = 1; k < BY; ++k) if (xv[k] > xv[bi]) bi = k;
    int gi = xv[BY];

    float ssum[EMB];
#pragma unroll
    for (int k = 0; k < EMB; ++k) ssum[k] = 0.f;
#pragma unroll
    for (int j = 0; j < NSYMP; ++j) {
        const float* row = &sS[(j * NOPT + xv[BY + 1 + j]) * EMB];
#pragma unroll
        for (int k = 0; k < EMB; ++k) ssum[k] += row[k];
    }

    float h[EMB];
#pragma unroll
    for (int k = 0; k < EMB; ++k)
        h[k] = (sB[bi * EMB + k] + sG[gi * EMB + k] + ssum[k] * (1.f / 15.f)) * (1.f / 3.f);

    float hp[HID];
#pragma unroll
    for (int j = 0; j < HID; ++j) hp[j] = 0.f;
#pragma unroll
    for (int k = 0; k < EMB; ++k) {
        float hv = h[k];
#pragma unroll
        for (int j = 0; j < HID; ++j) hp[j] += hv * sW[k * HID + j];
    }

    float dv = dinv[i];
    float4* o = (float4*)(hs1 + (size_t)i * HID);
#pragma unroll
    for (int q = 0; q < 4; ++q) {
        float4 v;
        v.x = dv * hp[q * 4 + 0];
        v.y = dv * hp[q * 4 + 1];
        v.z = dv * hp[q * 4 + 2];
        v.w = dv * hp[q * 4 + 3];
        o[q] = v;
    }
}

// ---- CSR gather + ELU + W2 projection (layer 1 -> hs2) ----
// 16 lanes per node, lane l owns HID component l.
__global__ __launch_bounds__(256) void k_gmid(const unsigned int* __restrict__ rowptr,
                                              const int* __restrict__ col,
                                              const float* __restrict__ A,   // hs1
                                              const float* __restrict__ dinv,
                                              const float* __restrict__ W2,
                                              const float* __restrict__ b1,
                                              float* __restrict__ B,         // hs2
                                              int n) {
    __shared__ float sW[HID * HID];
    __shared__ float sb[HID];
    if (threadIdx.x < HID * HID) sW[threadIdx.x] = W2[threadIdx.x];
    if (threadIdx.x < HID) sb[threadIdx.x] = b1[threadIdx.x];
    __syncthreads();

    int g = threadIdx.x >> 4, l = threadIdx.x & 15;
    int i = blockIdx.x * 16 + g;
    if (i >= n) return;

    unsigned int r0 = rowptr[i], r1 = rowptr[i + 1];
    float acc = 0.f;
    unsigned int e = r0;
    for (; e + 4 <= r1; e += 4) {
        int s0 = col[e], s1 = col[e + 1], s2 = col[e + 2], s3 = col[e + 3];
        float a0 = A[(size_t)s0 * HID + l];
        float a1 = A[(size_t)s1 * HID + l];
        float a2 = A[(size_t)s2 * HID + l];
        float a3 = A[(size_t)s3 * HID + l];
        acc += (a0 + a1) + (a2 + a3);
    }
    for (; e < r1; ++e) acc += A[(size_t)col[e] * HID + l];

    float dv = dinv[i];
    float v = dv * (acc + A[(size_t)i * HID + l]) + sb[l];
    float h1 = (v > 0.f) ? v : expm1f(v);

    int base = (threadIdx.x & 63) & ~15;  // 16-lane group base within wave
    float hp = 0.f;
#pragma unroll
    for (int k = 0; k < HID; ++k) {
        float h1k = __shfl(h1, base + k, 64);
        hp += h1k * sW[k * HID + l];
    }
    B[(size_t)i * HID + l] = dv * hp;
}

// ---- CSR gather + final linear (layer 2 -> out) ----
__global__ __launch_bounds__(256) void k_gfin(const unsigned int* __restrict__ rowptr,
                                              const int* __restrict__ col,
                                              const float* __restrict__ B,   // hs2
                                              const float* __restrict__ dinv,
                                              const float* __restrict__ b2,
                                              const float* __restrict__ Wl,
                                              const float* __restrict__ bl,
                                              float* __restrict__ out, int n) {
    __shared__ float sb[HID];
    __shared__ float sw[HID];
    __shared__ float sbl;
    if (threadIdx.x < HID) { sb[threadIdx.x] = b2[threadIdx.x]; sw[threadIdx.x] = Wl[threadIdx.x]; }
    if (threadIdx.x == 0) sbl = bl[0];
    __syncthreads();

    int g = threadIdx.x >> 4, l = threadIdx.x & 15;
    int i = blockIdx.x * 16 + g;
    if (i >= n) return;

    unsigned int r0 = rowptr[i], r1 = rowptr[i + 1];
    float acc = 0.f;
    unsigned int e = r0;
    for (; e + 4 <= r1; e += 4) {
        int s0 = col[e], s1 = col[e + 1], s2 = col[e + 2], s3 = col[e + 3];
        float a0 = B[(size_t)s0 * HID + l];
        float a1 = B[(size_t)s1 * HID + l];
        float a2 = B[(size_t)s2 * HID + l];
        float a3 = B[(size_t)s3 * HID + l];
        acc += (a0 + a1) + (a2 + a3);
    }
    for (; e < r1; ++e) acc += B[(size_t)col[e] * HID + l];

    float dv = dinv[i];
    float v = dv * (acc + B[(size_t)i * HID + l]) + sb[l];
    float p = v * sw[l];
#pragma unroll
    for (int off = 8; off > 0; off >>= 1) p += __shfl_xor(p, off, 64);
    if (l == 0) out[i] = p + sbl;
}

extern "C" void kernel_launch(void* const* d_in, const int* in_sizes, int n_in,
                              void* d_out, int out_size, void* d_ws, size_t ws_size,
                              hipStream_t stream) {
    const int*   x        = (const int*)d_in[0];
    const int*   ei       = (const int*)d_in[1];   // int32 per harness conversion
    const float* birth_t  = (const float*)d_in[2];
    const float* gender_t = (const float*)d_in[3];
    const float* symp_t   = (const float*)d_in[4];
    const float* W1       = (const float*)d_in[5];
    const float* b1       = (const float*)d_in[6];
    const float* W2       = (const float*)d_in[7];
    const float* b2       = (const float*)d_in[8];
    const float* Wl       = (const float*)d_in[9];
    const float* bl       = (const float*)d_in[10];
    float*       out      = (float*)d_out;

    const int n  = in_sizes[0] / XCOLS;
    const int nE = in_sizes[1] / 2;
    const int* src = ei;
    const int* tgt = ei + nE;

    // workspace layout (256B aligned slices)
    char* ws = (char*)d_ws;
    size_t off = 0;
    auto alloc = [&](size_t bytes) { char* p = ws + off; off = (off + bytes + 255) & ~(size_t)255; return p; };
    unsigned int* deg    = (unsigned int*)alloc((size_t)n * 4);
    float*        dinv   = (float*)alloc((size_t)n * 4);
    unsigned int* rowptr = (unsigned int*)alloc(((size_t)n + 1) * 4);
    unsigned int* bsum   = (unsigned int*)alloc(512 * 4);
    unsigned int* boff   = (unsigned int*)alloc(512 * 4);
    unsigned int* pos    = (unsigned int*)alloc((size_t)nE * 4);
    int*          col    = (int*)alloc((size_t)nE * 4);
    float*        A      = (float*)alloc((size_t)n * HID * 4);
    float*        B      = (float*)alloc((size_t)n * HID * 4);

    const int BLK = 256;
    const int gN  = (n + BLK - 1) / BLK;
    const int gE  = (nE + BLK - 1) / BLK;
    const int gNode = (n + 15) / 16;           // 16 nodes per 256-thread block
    const int nb  = (n + SCAN_B - 1) / SCAN_B; // scan blocks (<=128)

    hipMemsetAsync(deg, 0, (size_t)n * 4, stream);

    k_degpos<<<gE, BLK, 0, stream>>>(tgt, deg, pos, nE);
    k_bsum  <<<nb, SCAN_T, 0, stream>>>(deg, bsum, n);
    k_bscan <<<1, 128, 0, stream>>>(bsum, boff, nb);
    k_scan2 <<<nb, SCAN_T, 0, stream>>>(deg, boff, rowptr, n, nE);
    k_dinv  <<<gN, BLK, 0, stream>>>(deg, dinv, n);
    k_embed <<<gN, BLK, 0, stream>>>(x, birth_t, gender_t, symp_t, W1, dinv, A, n);
    k_scatter<<<gE, BLK, 0, stream>>>(src, tgt, pos, rowptr, col, nE);
    k_gmid  <<<gNode, BLK, 0, stream>>>(rowptr, col, A, dinv, W2, b1, B, n);
    k_gfin  <<<gNode, BLK, 0, stream>>>(rowptr, col, B, dinv, b2, Wl, bl, out, n);
}

// Round 4
// 382.857 us; speedup vs baseline: 27.8132x; 1.5255x over previous
//
#include <hip/hip_runtime.h>
#include <math.h>

#define EMB 32
#define HID 16
#define BY 4
#define NSYMP 15
#define NOPT 3
#define XCOLS (BY + 1 + NSYMP)   // 20

#define BSHIFT 9                 // 512 nodes per bucket
#define BSZ 512
#define EPB 8192                 // edges per hist/scatter block

#define SCAN_T 256
#define SCAN_E 16
#define SCAN_B (SCAN_T * SCAN_E)  // 4096 elements per block; M <= 128*4096 supported

// ---- level-1: per-block bucket histogram (no device atomics) ----
__global__ __launch_bounds__(256) void k_hist(const int* __restrict__ tgt,
                                              unsigned int* __restrict__ H,
                                              int nE, int gb1, int nbuck) {
    __shared__ unsigned int h[BSZ];
    int b = blockIdx.x, tid = threadIdx.x;
    h[tid] = 0; h[tid + 256] = 0;
    __syncthreads();
    int e0 = b * EPB;
#pragma unroll
    for (int k = 0; k < EPB / 256; ++k) {
        int e = e0 + k * 256 + tid;
        if (e < nE) atomicAdd(&h[tgt[e] >> BSHIFT], 1u);
    }
    __syncthreads();
    for (int q = tid; q < nbuck; q += 256) H[(size_t)q * gb1 + b] = h[q];
}

// ---- scan step 1: per-block sums ----
__global__ __launch_bounds__(256) void k_bsum(const unsigned int* __restrict__ A,
                                              unsigned int* __restrict__ bsum, int m) {
    __shared__ unsigned int s[SCAN_T];
    int base = blockIdx.x * SCAN_B + threadIdx.x * SCAN_E;
    unsigned int t = 0;
#pragma unroll
    for (int k = 0; k < SCAN_E; ++k) { int idx = base + k; if (idx < m) t += A[idx]; }
    s[threadIdx.x] = t; __syncthreads();
    for (int off = SCAN_T / 2; off > 0; off >>= 1) {
        if (threadIdx.x < off) s[threadIdx.x] += s[threadIdx.x + off];
        __syncthreads();
    }
    if (threadIdx.x == 0) bsum[blockIdx.x] = s[0];
}

// ---- scan step 2: exclusive scan of block sums (single block, nb <= 128) ----
__global__ __launch_bounds__(128) void k_bscan(const unsigned int* __restrict__ bsum,
                                               unsigned int* __restrict__ boff, int nb) {
    __shared__ unsigned int s[128];
    unsigned int v = (threadIdx.x < (unsigned)nb) ? bsum[threadIdx.x] : 0u;
    s[threadIdx.x] = v; __syncthreads();
    for (int off = 1; off < 128; off <<= 1) {
        unsigned int t = (threadIdx.x >= (unsigned)off) ? s[threadIdx.x - off] : 0u;
        __syncthreads();
        s[threadIdx.x] += t;
        __syncthreads();
    }
    if (threadIdx.x < (unsigned)nb) boff[threadIdx.x] = s[threadIdx.x] - v;
}

// ---- scan step 3: per-element exclusive prefix (+ sentinel S[m]=total) ----
__global__ __launch_bounds__(256) void k_scan2(const unsigned int* __restrict__ A,
                                               const unsigned int* __restrict__ boff,
                                               unsigned int* __restrict__ S, int m, int total) {
    __shared__ unsigned int s[SCAN_T];
    int tid = threadIdx.x;
    int base = blockIdx.x * SCAN_B + tid * SCAN_E;
    unsigned int loc[SCAN_E];
    unsigned int t = 0;
#pragma unroll
    for (int k = 0; k < SCAN_E; ++k) {
        int idx = base + k;
        unsigned int d = (idx < m) ? A[idx] : 0u;
        loc[k] = t; t += d;
    }
    s[tid] = t; __syncthreads();
    unsigned int own = t;
    for (int off = 1; off < SCAN_T; off <<= 1) {
        unsigned int u = (tid >= off) ? s[tid - off] : 0u;
        __syncthreads();
        s[tid] += u;
        __syncthreads();
    }
    unsigned int texcl = s[tid] - own;
    unsigned int b = boff[blockIdx.x];
#pragma unroll
    for (int k = 0; k < SCAN_E; ++k) {
        int idx = base + k;
        if (idx < m) S[idx] = b + texcl + loc[k];
    }
    if (blockIdx.x == 0 && tid == 0) S[m] = (unsigned int)total;
}

// ---- level-1 scatter: edges -> bucket-grouped packed array (LDS atomics only) ----
__global__ __launch_bounds__(256) void k_scat(const int* __restrict__ tgt,
                                              const int* __restrict__ src,
                                              const unsigned int* __restrict__ S,
                                              int* __restrict__ bp,
                                              int nE, int gb1, int nbuck) {
    __shared__ unsigned int cur[BSZ];
    int b = blockIdx.x, tid = threadIdx.x;
    for (int q = tid; q < nbuck; q += 256) cur[q] = S[(size_t)q * gb1 + b];
    __syncthreads();
    int e0 = b * EPB;
#pragma unroll
    for (int k = 0; k < EPB / 256; ++k) {
        int e = e0 + k * 256 + tid;
        if (e < nE) {
            int t = tgt[e];
            unsigned int slot = atomicAdd(&cur[t >> BSHIFT], 1u);
            bp[slot] = (src[e] << BSHIFT) | (t & (BSZ - 1));
        }
    }
}

// ---- level-2: per-bucket fine CSR + dinv (LDS atomics only) ----
__global__ __launch_bounds__(256) void k_bcsr(const unsigned int* __restrict__ S,
                                              const int* __restrict__ bp,
                                              unsigned int* __restrict__ rowptr,
                                              int* __restrict__ col,
                                              float* __restrict__ dinv,
                                              int n, int nE, int gb1, int nbuck) {
    __shared__ unsigned int h[BSZ];
    __shared__ unsigned int ps[256];
    __shared__ unsigned int cur[BSZ];
    int q = blockIdx.x, tid = threadIdx.x;
    int base = q << BSHIFT;
    h[tid] = 0; h[tid + 256] = 0;
    __syncthreads();
    unsigned int e0 = S[(size_t)q * gb1];
    unsigned int e1 = S[(size_t)(q + 1) * gb1];
    for (unsigned int e = e0 + tid; e < e1; e += 256)
        atomicAdd(&h[bp[e] & (BSZ - 1)], 1u);
    __syncthreads();
    unsigned int a = h[2 * tid], bb = h[2 * tid + 1];
    unsigned int pair = a + bb;
    ps[tid] = pair; __syncthreads();
    for (int off = 1; off < 256; off <<= 1) {
        unsigned int t = (tid >= off) ? ps[tid - off] : 0u;
        __syncthreads();
        ps[tid] += t;
        __syncthreads();
    }
    unsigned int excl = ps[tid] - pair;
    unsigned int r0 = e0 + excl;
    unsigned int r1 = r0 + a;
    cur[2 * tid] = r0; cur[2 * tid + 1] = r1;
    int n0 = base + 2 * tid, n1 = n0 + 1;
    if (n0 < n) {
        rowptr[n0] = r0;
        float d = (float)(a + 1u); float r = rsqrtf(d);
        r = r * (1.5f - 0.5f * d * r * r); dinv[n0] = r;
    }
    if (n1 < n) {
        rowptr[n1] = r1;
        float d = (float)(bb + 1u); float r = rsqrtf(d);
        r = r * (1.5f - 0.5f * d * r * r); dinv[n1] = r;
    }
    if (q == nbuck - 1 && tid == 0) rowptr[n] = (unsigned int)nE;
    __syncthreads();
    for (unsigned int e = e0 + tid; e < e1; e += 256) {
        int v = bp[e];
        unsigned int slot = atomicAdd(&cur[v & (BSZ - 1)], 1u);
        col[slot] = v >> BSHIFT;
    }
}

// ---- embeddings + h@W1, pre-scaled by dinv ----
__global__ __launch_bounds__(256) void k_embed(const int* __restrict__ x,
                                               const float* __restrict__ birth_t,
                                               const float* __restrict__ gender_t,
                                               const float* __restrict__ symp_t,
                                               const float* __restrict__ W1,
                                               const float* __restrict__ dinv,
                                               float* __restrict__ hs1, int n) {
    __shared__ float sB[BY * EMB];
    __shared__ float sG[2 * EMB];
    __shared__ float sS[NSYMP * NOPT * EMB];
    __shared__ float sW[EMB * HID];
    for (int k = threadIdx.x; k < BY * EMB; k += blockDim.x) sB[k] = birth_t[k];
    for (int k = threadIdx.x; k < 2 * EMB; k += blockDim.x) sG[k] = gender_t[k];
    for (int k = threadIdx.x; k < NSYMP * NOPT * EMB; k += blockDim.x) sS[k] = symp_t[k];
    for (int k = threadIdx.x; k < EMB * HID; k += blockDim.x) sW[k] = W1[k];
    __syncthreads();

    int i = blockIdx.x * blockDim.x + threadIdx.x;
    if (i >= n) return;

    const int* xr = x + (size_t)i * XCOLS;
    int xv[XCOLS];
#pragma unroll
    for (int k = 0; k < XCOLS; ++k) xv[k] = xr[k];

    int bi = 0;
#pragma unroll
    for (int k = 1; k < BY; ++k) if (xv[k] > xv[bi]) bi = k;
    int gi = xv[BY];

    float ssum[EMB];
#pragma unroll
    for (int k = 0; k < EMB; ++k) ssum[k] = 0.f;
#pragma unroll
    for (int j = 0; j < NSYMP; ++j) {
        const float* row = &sS[(j * NOPT + xv[BY + 1 + j]) * EMB];
#pragma unroll
        for (int k = 0; k < EMB; ++k) ssum[k] += row[k];
    }

    float h[EMB];
#pragma unroll
    for (int k = 0; k < EMB; ++k)
        h[k] = (sB[bi * EMB + k] + sG[gi * EMB + k] + ssum[k] * (1.f / 15.f)) * (1.f / 3.f);

    float hp[HID];
#pragma unroll
    for (int j = 0; j < HID; ++j) hp[j] = 0.f;
#pragma unroll
    for (int k = 0; k < EMB; ++k) {
        float hv = h[k];
#pragma unroll
        for (int j = 0; j < HID; ++j) hp[j] += hv * sW[k * HID + j];
    }

    float dv = dinv[i];
    float4* o = (float4*)(hs1 + (size_t)i * HID);
#pragma unroll
    for (int q = 0; q < 4; ++q) {
        float4 v;
        v.x = dv * hp[q * 4 + 0];
        v.y = dv * hp[q * 4 + 1];
        v.z = dv * hp[q * 4 + 2];
        v.w = dv * hp[q * 4 + 3];
        o[q] = v;
    }
}

// ---- CSR gather + ELU + W2 projection (layer 1 -> hs2) ----
__global__ __launch_bounds__(256) void k_gmid(const unsigned int* __restrict__ rowptr,
                                              const int* __restrict__ col,
                                              const float* __restrict__ A,
                                              const float* __restrict__ dinv,
                                              const float* __restrict__ W2,
                                              const float* __restrict__ b1,
                                              float* __restrict__ B,
                                              int n) {
    __shared__ float sW[HID * HID];
    __shared__ float sb[HID];
    if (threadIdx.x < HID * HID) sW[threadIdx.x] = W2[threadIdx.x];
    if (threadIdx.x < HID) sb[threadIdx.x] = b1[threadIdx.x];
    __syncthreads();

    int g = threadIdx.x >> 4, l = threadIdx.x & 15;
    int i = blockIdx.x * 16 + g;
    if (i >= n) return;

    unsigned int r0 = rowptr[i], r1 = rowptr[i + 1];
    float acc = 0.f;
    unsigned int e = r0;
    for (; e + 4 <= r1; e += 4) {
        int s0 = col[e], s1 = col[e + 1], s2 = col[e + 2], s3 = col[e + 3];
        float a0 = A[(size_t)s0 * HID + l];
        float a1 = A[(size_t)s1 * HID + l];
        float a2 = A[(size_t)s2 * HID + l];
        float a3 = A[(size_t)s3 * HID + l];
        acc += (a0 + a1) + (a2 + a3);
    }
    for (; e < r1; ++e) acc += A[(size_t)col[e] * HID + l];

    float dv = dinv[i];
    float v = dv * (acc + A[(size_t)i * HID + l]) + sb[l];
    float h1 = (v > 0.f) ? v : expm1f(v);

    int base = (threadIdx.x & 63) & ~15;
    float hp = 0.f;
#pragma unroll
    for (int k = 0; k < HID; ++k) {
        float h1k = __shfl(h1, base + k, 64);
        hp += h1k * sW[k * HID + l];
    }
    B[(size_t)i * HID + l] = dv * hp;
}

// ---- CSR gather + final linear (layer 2 -> out) ----
__global__ __launch_bounds__(256) void k_gfin(const unsigned int* __restrict__ rowptr,
                                              const int* __restrict__ col,
                                              const float* __restrict__ B,
                                              const float* __restrict__ dinv,
                                              const float* __restrict__ b2,
                                              const float* __restrict__ Wl,
                                              const float* __restrict__ bl,
                                              float* __restrict__ out, int n) {
    __shared__ float sb[HID];
    __shared__ float sw[HID];
    __shared__ float sbl;
    if (threadIdx.x < HID) { sb[threadIdx.x] = b2[threadIdx.x]; sw[threadIdx.x] = Wl[threadIdx.x]; }
    if (threadIdx.x == 0) sbl = bl[0];
    __syncthreads();

    int g = threadIdx.x >> 4, l = threadIdx.x & 15;
    int i = blockIdx.x * 16 + g;
    if (i >= n) return;

    unsigned int r0 = rowptr[i], r1 = rowptr[i + 1];
    float acc = 0.f;
    unsigned int e = r0;
    for (; e + 4 <= r1; e += 4) {
        int s0 = col[e], s1 = col[e + 1], s2 = col[e + 2], s3 = col[e + 3];
        float a0 = B[(size_t)s0 * HID + l];
        float a1 = B[(size_t)s1 * HID + l];
        float a2 = B[(size_t)s2 * HID + l];
        float a3 = B[(size_t)s3 * HID + l];
        acc += (a0 + a1) + (a2 + a3);
    }
    for (; e < r1; ++e) acc += B[(size_t)col[e] * HID + l];

    float dv = dinv[i];
    float v = dv * (acc + B[(size_t)i * HID + l]) + sb[l];
    float p = v * sw[l];
#pragma unroll
    for (int off = 8; off > 0; off >>= 1) p += __shfl_xor(p, off, 64);
    if (l == 0) out[i] = p + sbl;
}

extern "C" void kernel_launch(void* const* d_in, const int* in_sizes, int n_in,
                              void* d_out, int out_size, void* d_ws, size_t ws_size,
                              hipStream_t stream) {
    const int*   x        = (const int*)d_in[0];
    const int*   ei       = (const int*)d_in[1];   // int32 per harness conversion
    const float* birth_t  = (const float*)d_in[2];
    const float* gender_t = (const float*)d_in[3];
    const float* symp_t   = (const float*)d_in[4];
    const float* W1       = (const float*)d_in[5];
    const float* b1       = (const float*)d_in[6];
    const float* W2       = (const float*)d_in[7];
    const float* b2       = (const float*)d_in[8];
    const float* Wl       = (const float*)d_in[9];
    const float* bl       = (const float*)d_in[10];
    float*       out      = (float*)d_out;

    const int n  = in_sizes[0] / XCOLS;
    const int nE = in_sizes[1] / 2;
    const int* src = ei;
    const int* tgt = ei + nE;

    const int nbuck = (n + BSZ - 1) >> BSHIFT;           // 391 for n=200000
    const int gb1   = (nE + EPB - 1) / EPB;              // 782 for nE=6.4M
    const int M     = nbuck * gb1;                        // ~306k
    const int nb    = (M + SCAN_B - 1) / SCAN_B;          // <=128

    // workspace layout (256B aligned slices)
    char* ws = (char*)d_ws;
    size_t off = 0;
    auto alloc = [&](size_t bytes) { char* p = ws + off; off = (off + bytes + 255) & ~(size_t)255; return p; };
    unsigned int* H      = (unsigned int*)alloc((size_t)M * 4);
    unsigned int* S      = (unsigned int*)alloc(((size_t)M + 1) * 4);
    unsigned int* bsum   = (unsigned int*)alloc(512 * 4);
    unsigned int* boff   = (unsigned int*)alloc(512 * 4);
    int*          bp     = (int*)alloc((size_t)nE * 4);
    int*          col    = (int*)alloc((size_t)nE * 4);
    unsigned int* rowptr = (unsigned int*)alloc(((size_t)n + 1) * 4);
    float*        dinv   = (float*)alloc((size_t)n * 4);
    float*        A      = (float*)alloc((size_t)n * HID * 4);
    float*        B      = (float*)alloc((size_t)n * HID * 4);

    const int BLK = 256;
    const int gN    = (n + BLK - 1) / BLK;
    const int gNode = (n + 15) / 16;

    k_hist <<<gb1, BLK, 0, stream>>>(tgt, H, nE, gb1, nbuck);
    k_bsum <<<nb, SCAN_T, 0, stream>>>(H, bsum, M);
    k_bscan<<<1, 128, 0, stream>>>(bsum, boff, nb);
    k_scan2<<<nb, SCAN_T, 0, stream>>>(H, boff, S, M, nE);
    k_scat <<<gb1, BLK, 0, stream>>>(tgt, src, S, bp, nE, gb1, nbuck);
    k_bcsr <<<nbuck, BLK, 0, stream>>>(S, bp, rowptr, col, dinv, n, nE, gb1, nbuck);
    k_embed<<<gN, BLK, 0, stream>>>(x, birth_t, gender_t, symp_t, W1, dinv, A, n);
    k_gmid <<<gNode, BLK, 0, stream>>>(rowptr, col, A, dinv, W2, b1, B, n);
    k_gfin <<<gNode, BLK, 0, stream>>>(rowptr, col, B, dinv, b2, Wl, bl, out, n);
}

// Round 5
// 373.700 us; speedup vs baseline: 28.4948x; 1.0245x over previous
//
#include <hip/hip_runtime.h>
#include <math.h>

#define EMB 32
#define HID 16
#define BY 4
#define NSYMP 15
#define NOPT 3
#define XCOLS (BY + 1 + NSYMP)   // 20

#define BSHIFT 9                 // 512 nodes per bucket
#define BSZ 512
#define EPB 8192                 // edges per hist/scatter block

#define SCAN_T 256
#define SCAN_E 16
#define SCAN_B (SCAN_T * SCAN_E)  // 4096 elements per block; M <= 128*4096 supported

// ---- level-1: per-block bucket histogram (no device atomics) ----
__global__ __launch_bounds__(256) void k_hist(const int* __restrict__ tgt,
                                              unsigned int* __restrict__ H,
                                              int nE, int gb1, int nbuck) {
    __shared__ unsigned int h[BSZ];
    int b = blockIdx.x, tid = threadIdx.x;
    h[tid] = 0; h[tid + 256] = 0;
    __syncthreads();
    int e0 = b * EPB;
#pragma unroll
    for (int k = 0; k < EPB / 256; ++k) {
        int e = e0 + k * 256 + tid;
        if (e < nE) atomicAdd(&h[(unsigned)tgt[e] >> BSHIFT], 1u);
    }
    __syncthreads();
    for (int q = tid; q < nbuck; q += 256) H[(size_t)q * gb1 + b] = h[q];
}

// ---- scan step 1: per-block sums ----
__global__ __launch_bounds__(256) void k_bsum(const unsigned int* __restrict__ A,
                                              unsigned int* __restrict__ bsum, int m) {
    __shared__ unsigned int s[SCAN_T];
    int base = blockIdx.x * SCAN_B + threadIdx.x * SCAN_E;
    unsigned int t = 0;
#pragma unroll
    for (int k = 0; k < SCAN_E; ++k) { int idx = base + k; if (idx < m) t += A[idx]; }
    s[threadIdx.x] = t; __syncthreads();
    for (int off = SCAN_T / 2; off > 0; off >>= 1) {
        if (threadIdx.x < off) s[threadIdx.x] += s[threadIdx.x + off];
        __syncthreads();
    }
    if (threadIdx.x == 0) bsum[blockIdx.x] = s[0];
}

// ---- scan step 2: exclusive scan of block sums (single block, nb <= 128) ----
__global__ __launch_bounds__(128) void k_bscan(const unsigned int* __restrict__ bsum,
                                               unsigned int* __restrict__ boff, int nb) {
    __shared__ unsigned int s[128];
    unsigned int v = (threadIdx.x < (unsigned)nb) ? bsum[threadIdx.x] : 0u;
    s[threadIdx.x] = v; __syncthreads();
    for (int off = 1; off < 128; off <<= 1) {
        unsigned int t = (threadIdx.x >= (unsigned)off) ? s[threadIdx.x - off] : 0u;
        __syncthreads();
        s[threadIdx.x] += t;
        __syncthreads();
    }
    if (threadIdx.x < (unsigned)nb) boff[threadIdx.x] = s[threadIdx.x] - v;
}

// ---- scan step 3: per-element exclusive prefix (+ sentinel S[m]=total) ----
__global__ __launch_bounds__(256) void k_scan2(const unsigned int* __restrict__ A,
                                               const unsigned int* __restrict__ boff,
                                               unsigned int* __restrict__ S, int m, int total) {
    __shared__ unsigned int s[SCAN_T];
    int tid = threadIdx.x;
    int base = blockIdx.x * SCAN_B + tid * SCAN_E;
    unsigned int loc[SCAN_E];
    unsigned int t = 0;
#pragma unroll
    for (int k = 0; k < SCAN_E; ++k) {
        int idx = base + k;
        unsigned int d = (idx < m) ? A[idx] : 0u;
        loc[k] = t; t += d;
    }
    s[tid] = t; __syncthreads();
    unsigned int own = t;
    for (int off = 1; off < SCAN_T; off <<= 1) {
        unsigned int u = (tid >= off) ? s[tid - off] : 0u;
        __syncthreads();
        s[tid] += u;
        __syncthreads();
    }
    unsigned int texcl = s[tid] - own;
    unsigned int b = boff[blockIdx.x];
#pragma unroll
    for (int k = 0; k < SCAN_E; ++k) {
        int idx = base + k;
        if (idx < m) S[idx] = b + texcl + loc[k];
    }
    if (blockIdx.x == 0 && tid == 0) S[m] = (unsigned int)total;
}

// ---- level-1 scatter, LDS-staged: edges -> bucket-grouped packed array,
//      global writes are contiguous per bucket (no write amplification) ----
__global__ __launch_bounds__(256) void k_scat(const int* __restrict__ tgt,
                                              const int* __restrict__ src,
                                              const unsigned int* __restrict__ S,
                                              int* __restrict__ bp,
                                              int nE, int gb1, int nbuck) {
    __shared__ int bpv[EPB];                 // 32 KB staged payload (bucket-grouped)
    __shared__ unsigned short qid[EPB];      // 16 KB bucket id per staged slot
    __shared__ unsigned int cur[BSZ];        // cursors
    __shared__ unsigned int dif[BSZ];        // S[q*gb1+b] - local_base[q]
    __shared__ unsigned int ps[256];
    int b = blockIdx.x, tid = threadIdx.x;
    cur[tid] = 0; cur[tid + 256] = 0;
    __syncthreads();
    int e0 = b * EPB;
    int ecnt = min(EPB, nE - e0);

    // pass 1: local histogram
    for (int k = tid; k < ecnt; k += 256)
        atomicAdd(&cur[(unsigned)tgt[e0 + k] >> BSHIFT], 1u);
    __syncthreads();

    // exclusive scan of 512 counters (2 per thread)
    unsigned int a = cur[2 * tid], c = cur[2 * tid + 1];
    unsigned int pair = a + c;
    ps[tid] = pair; __syncthreads();
    for (int off = 1; off < 256; off <<= 1) {
        unsigned int t = (tid >= off) ? ps[tid - off] : 0u;
        __syncthreads();
        ps[tid] += t;
        __syncthreads();
    }
    unsigned int excl = ps[tid] - pair;
    cur[2 * tid] = excl; cur[2 * tid + 1] = excl + a;       // cursors = local base
    dif[2 * tid] = excl; dif[2 * tid + 1] = excl + a;       // stash local base
    __syncthreads();
    // dif[q] = global_base - local_base
    for (int q = tid; q < nbuck; q += 256)
        dif[q] = S[(size_t)q * gb1 + b] - dif[q];
    __syncthreads();

    // pass 2: scatter edges into LDS, grouped by bucket
    for (int k = tid; k < ecnt; k += 256) {
        int t = tgt[e0 + k];
        int q = (unsigned)t >> BSHIFT;
        unsigned int lpos = atomicAdd(&cur[q], 1u);
        bpv[lpos] = (src[e0 + k] << BSHIFT) | (t & (BSZ - 1));
        qid[lpos] = (unsigned short)q;
    }
    __syncthreads();

    // pass 3: linear flush -> contiguous global writes per bucket
    for (int k = tid; k < ecnt; k += 256) {
        int q = qid[k];
        bp[dif[q] + k] = bpv[k];
    }
}

// ---- level-2: per-bucket fine CSR + dinv (LDS atomics only) ----
__global__ __launch_bounds__(256) void k_bcsr(const unsigned int* __restrict__ S,
                                              const int* __restrict__ bp,
                                              unsigned int* __restrict__ rowptr,
                                              int* __restrict__ col,
                                              float* __restrict__ dinv,
                                              int n, int nE, int gb1, int nbuck) {
    __shared__ unsigned int h[BSZ];
    __shared__ unsigned int ps[256];
    __shared__ unsigned int cur[BSZ];
    int q = blockIdx.x, tid = threadIdx.x;
    int base = q << BSHIFT;
    h[tid] = 0; h[tid + 256] = 0;
    __syncthreads();
    unsigned int e0 = S[(size_t)q * gb1];
    unsigned int e1 = S[(size_t)(q + 1) * gb1];
    for (unsigned int e = e0 + tid; e < e1; e += 256)
        atomicAdd(&h[bp[e] & (BSZ - 1)], 1u);
    __syncthreads();
    unsigned int a = h[2 * tid], bb = h[2 * tid + 1];
    unsigned int pair = a + bb;
    ps[tid] = pair; __syncthreads();
    for (int off = 1; off < 256; off <<= 1) {
        unsigned int t = (tid >= off) ? ps[tid - off] : 0u;
        __syncthreads();
        ps[tid] += t;
        __syncthreads();
    }
    unsigned int excl = ps[tid] - pair;
    unsigned int r0 = e0 + excl;
    unsigned int r1 = r0 + a;
    cur[2 * tid] = r0; cur[2 * tid + 1] = r1;
    int n0 = base + 2 * tid, n1 = n0 + 1;
    if (n0 < n) {
        rowptr[n0] = r0;
        float d = (float)(a + 1u); float r = rsqrtf(d);
        r = r * (1.5f - 0.5f * d * r * r); dinv[n0] = r;
    }
    if (n1 < n) {
        rowptr[n1] = r1;
        float d = (float)(bb + 1u); float r = rsqrtf(d);
        r = r * (1.5f - 0.5f * d * r * r); dinv[n1] = r;
    }
    if (q == nbuck - 1 && tid == 0) rowptr[n] = (unsigned int)nE;
    __syncthreads();
    for (unsigned int e = e0 + tid; e < e1; e += 256) {
        int v = bp[e];
        unsigned int slot = atomicAdd(&cur[v & (BSZ - 1)], 1u);
        col[slot] = v >> BSHIFT;
    }
}

// ---- embeddings + h@W1, pre-scaled by dinv ----
__global__ __launch_bounds__(256) void k_embed(const int* __restrict__ x,
                                               const float* __restrict__ birth_t,
                                               const float* __restrict__ gender_t,
                                               const float* __restrict__ symp_t,
                                               const float* __restrict__ W1,
                                               const float* __restrict__ dinv,
                                               float* __restrict__ hs1, int n) {
    __shared__ float sB[BY * EMB];
    __shared__ float sG[2 * EMB];
    __shared__ float sS[NSYMP * NOPT * EMB];
    __shared__ float sW[EMB * HID];
    for (int k = threadIdx.x; k < BY * EMB; k += blockDim.x) sB[k] = birth_t[k];
    for (int k = threadIdx.x; k < 2 * EMB; k += blockDim.x) sG[k] = gender_t[k];
    for (int k = threadIdx.x; k < NSYMP * NOPT * EMB; k += blockDim.x) sS[k] = symp_t[k];
    for (int k = threadIdx.x; k < EMB * HID; k += blockDim.x) sW[k] = W1[k];
    __syncthreads();

    int i = blockIdx.x * blockDim.x + threadIdx.x;
    if (i >= n) return;

    const int* xr = x + (size_t)i * XCOLS;
    int xv[XCOLS];
#pragma unroll
    for (int k = 0; k < XCOLS; ++k) xv[k] = xr[k];

    int bi = 0;
#pragma unroll
    for (int k = 1; k < BY; ++k) if (xv[k] > xv[bi]) bi = k;
    int gi = xv[BY];

    float ssum[EMB];
#pragma unroll
    for (int k = 0; k < EMB; ++k) ssum[k] = 0.f;
#pragma unroll
    for (int j = 0; j < NSYMP; ++j) {
        const float* row = &sS[(j * NOPT + xv[BY + 1 + j]) * EMB];
#pragma unroll
        for (int k = 0; k < EMB; ++k) ssum[k] += row[k];
    }

    float h[EMB];
#pragma unroll
    for (int k = 0; k < EMB; ++k)
        h[k] = (sB[bi * EMB + k] + sG[gi * EMB + k] + ssum[k] * (1.f / 15.f)) * (1.f / 3.f);

    float hp[HID];
#pragma unroll
    for (int j = 0; j < HID; ++j) hp[j] = 0.f;
#pragma unroll
    for (int k = 0; k < EMB; ++k) {
        float hv = h[k];
#pragma unroll
        for (int j = 0; j < HID; ++j) hp[j] += hv * sW[k * HID + j];
    }

    float dv = dinv[i];
    float4* o = (float4*)(hs1 + (size_t)i * HID);
#pragma unroll
    for (int q = 0; q < 4; ++q) {
        float4 v;
        v.x = dv * hp[q * 4 + 0];
        v.y = dv * hp[q * 4 + 1];
        v.z = dv * hp[q * 4 + 2];
        v.w = dv * hp[q * 4 + 3];
        o[q] = v;
    }
}

// ---- CSR gather + ELU + W2 projection (layer 1 -> hs2) ----
__global__ __launch_bounds__(256) void k_gmid(const unsigned int* __restrict__ rowptr,
                                              const int* __restrict__ col,
                                              const float* __restrict__ A,
                                              const float* __restrict__ dinv,
                                              const float* __restrict__ W2,
                                              const float* __restrict__ b1,
                                              float* __restrict__ B,
                                              int n) {
    __shared__ float sW[HID * HID];
    __shared__ float sb[HID];
    if (threadIdx.x < HID * HID) sW[threadIdx.x] = W2[threadIdx.x];
    if (threadIdx.x < HID) sb[threadIdx.x] = b1[threadIdx.x];
    __syncthreads();

    int g = threadIdx.x >> 4, l = threadIdx.x & 15;
    int i = blockIdx.x * 16 + g;
    if (i >= n) return;

    unsigned int r0 = rowptr[i], r1 = rowptr[i + 1];
    float acc = 0.f;
    unsigned int e = r0;
    for (; e + 4 <= r1; e += 4) {
        int s0 = col[e], s1 = col[e + 1], s2 = col[e + 2], s3 = col[e + 3];
        float a0 = A[(size_t)s0 * HID + l];
        float a1 = A[(size_t)s1 * HID + l];
        float a2 = A[(size_t)s2 * HID + l];
        float a3 = A[(size_t)s3 * HID + l];
        acc += (a0 + a1) + (a2 + a3);
    }
    for (; e < r1; ++e) acc += A[(size_t)col[e] * HID + l];

    float dv = dinv[i];
    float v = dv * (acc + A[(size_t)i * HID + l]) + sb[l];
    float h1 = (v > 0.f) ? v : expm1f(v);

    int base = (threadIdx.x & 63) & ~15;
    float hp = 0.f;
#pragma unroll
    for (int k = 0; k < HID; ++k) {
        float h1k = __shfl(h1, base + k, 64);
        hp += h1k * sW[k * HID + l];
    }
    B[(size_t)i * HID + l] = dv * hp;
}

// ---- CSR gather + final linear (layer 2 -> out) ----
__global__ __launch_bounds__(256) void k_gfin(const unsigned int* __restrict__ rowptr,
                                              const int* __restrict__ col,
                                              const float* __restrict__ B,
                                              const float* __restrict__ dinv,
                                              const float* __restrict__ b2,
                                              const float* __restrict__ Wl,
                                              const float* __restrict__ bl,
                                              float* __restrict__ out, int n) {
    __shared__ float sb[HID];
    __shared__ float sw[HID];
    __shared__ float sbl;
    if (threadIdx.x < HID) { sb[threadIdx.x] = b2[threadIdx.x]; sw[threadIdx.x] = Wl[threadIdx.x]; }
    if (threadIdx.x == 0) sbl = bl[0];
    __syncthreads();

    int g = threadIdx.x >> 4, l = threadIdx.x & 15;
    int i = blockIdx.x * 16 + g;
    if (i >= n) return;

    unsigned int r0 = rowptr[i], r1 = rowptr[i + 1];
    float acc = 0.f;
    unsigned int e = r0;
    for (; e + 4 <= r1; e += 4) {
        int s0 = col[e], s1 = col[e + 1], s2 = col[e + 2], s3 = col[e + 3];
        float a0 = B[(size_t)s0 * HID + l];
        float a1 = B[(size_t)s1 * HID + l];
        float a2 = B[(size_t)s2 * HID + l];
        float a3 = B[(size_t)s3 * HID + l];
        acc += (a0 + a1) + (a2 + a3);
    }
    for (; e < r1; ++e) acc += B[(size_t)col[e] * HID + l];

    float dv = dinv[i];
    float v = dv * (acc + B[(size_t)i * HID + l]) + sb[l];
    float p = v * sw[l];
#pragma unroll
    for (int off = 8; off > 0; off >>= 1) p += __shfl_xor(p, off, 64);
    if (l == 0) out[i] = p + sbl;
}

extern "C" void kernel_launch(void* const* d_in, const int* in_sizes, int n_in,
                              void* d_out, int out_size, void* d_ws, size_t ws_size,
                              hipStream_t stream) {
    const int*   x        = (const int*)d_in[0];
    const int*   ei       = (const int*)d_in[1];   // int32 per harness conversion
    const float* birth_t  = (const float*)d_in[2];
    const float* gender_t = (const float*)d_in[3];
    const float* symp_t   = (const float*)d_in[4];
    const float* W1       = (const float*)d_in[5];
    const float* b1       = (const float*)d_in[6];
    const float* W2       = (const float*)d_in[7];
    const float* b2       = (const float*)d_in[8];
    const float* Wl       = (const float*)d_in[9];
    const float* bl       = (const float*)d_in[10];
    float*       out      = (float*)d_out;

    const int n  = in_sizes[0] / XCOLS;
    const int nE = in_sizes[1] / 2;
    const int* src = ei;
    const int* tgt = ei + nE;

    const int nbuck = (n + BSZ - 1) >> BSHIFT;           // 391 for n=200000
    const int gb1   = (nE + EPB - 1) / EPB;              // 782 for nE=6.4M
    const int M     = nbuck * gb1;                        // ~306k
    const int nb    = (M + SCAN_B - 1) / SCAN_B;          // <=128

    // workspace layout (256B aligned slices)
    char* ws = (char*)d_ws;
    size_t off = 0;
    auto alloc = [&](size_t bytes) { char* p = ws + off; off = (off + bytes + 255) & ~(size_t)255; return p; };
    unsigned int* H      = (unsigned int*)alloc((size_t)M * 4);
    unsigned int* S      = (unsigned int*)alloc(((size_t)M + 1) * 4);
    unsigned int* bsum   = (unsigned int*)alloc(512 * 4);
    unsigned int* boff   = (unsigned int*)alloc(512 * 4);
    int*          bp     = (int*)alloc((size_t)nE * 4);
    int*          col    = (int*)alloc((size_t)nE * 4);
    unsigned int* rowptr = (unsigned int*)alloc(((size_t)n + 1) * 4);
    float*        dinv   = (float*)alloc((size_t)n * 4);
    float*        A      = (float*)alloc((size_t)n * HID * 4);
    float*        B      = (float*)alloc((size_t)n * HID * 4);

    const int BLK = 256;
    const int gN    = (n + BLK - 1) / BLK;
    const int gNode = (n + 15) / 16;

    k_hist <<<gb1, BLK, 0, stream>>>(tgt, H, nE, gb1, nbuck);
    k_bsum <<<nb, SCAN_T, 0, stream>>>(H, bsum, M);
    k_bscan<<<1, 128, 0, stream>>>(bsum, boff, nb);
    k_scan2<<<nb, SCAN_T, 0, stream>>>(H, boff, S, M, nE);
    k_scat <<<gb1, BLK, 0, stream>>>(tgt, src, S, bp, nE, gb1, nbuck);
    k_bcsr <<<nbuck, BLK, 0, stream>>>(S, bp, rowptr, col, dinv, n, nE, gb1, nbuck);
    k_embed<<<gN, BLK, 0, stream>>>(x, birth_t, gender_t, symp_t, W1, dinv, A, n);
    k_gmid <<<gNode, BLK, 0, stream>>>(rowptr, col, A, dinv, W2, b1, B, n);
    k_gfin <<<gNode, BLK, 0, stream>>>(rowptr, col, B, dinv, b2, Wl, bl, out, n);
}